// Round 20
// baseline (139.286 us; speedup 1.0000x reference)
//
#include <hip/hip_runtime.h>
#include <hip/hip_bf16.h>

// Problem constants
#define BB 2
#define SS 2048
#define DD 1024
#define HH 16
#define DKK 64

typedef __attribute__((ext_vector_type(4))) float  f32x4;
typedef __attribute__((ext_vector_type(8))) short  s16x8;
typedef __attribute__((ext_vector_type(4))) short  s16x4;
typedef __attribute__((ext_vector_type(4))) float  fvec4;
typedef __attribute__((ext_vector_type(2))) unsigned int u32x2;
typedef __attribute__((ext_vector_type(4))) unsigned int u32x4;

__device__ __forceinline__ short f2bs(float f) {
    union { __hip_bfloat16 b; short s; } u;
    u.b = __float2bfloat16(f);
    return u.s;
}

// pack two f32 -> u32 of two bf16 (v_cvt_pk_bf16_f32; no builtin on gfx950)
__device__ __forceinline__ unsigned cvtpk(float lo, float hi) {
    unsigned r;
    asm("v_cvt_pk_bf16_f32 %0, %1, %2" : "=v"(r) : "v"(lo), "v"(hi));
    return r;
}

__device__ __forceinline__ void gload_lds16(const short* g, short* l) {
    __builtin_amdgcn_global_load_lds((const __attribute__((address_space(1))) void*)g,
                                     (__attribute__((address_space(3))) void*)l, 16, 0, 0);
}

// ---------------------------------------------------------------------------
// fp32 -> bf16 convert, WEIGHTS ONLY (24 MB traffic; q/k/v conversion is
// fused into the QKV GEMM's A-staging)
// ---------------------------------------------------------------------------
__global__ __launch_bounds__(256) void cvt_w(
    const float* __restrict__ wq, const float* __restrict__ wk,
    const float* __restrict__ wv, const float* __restrict__ wo,
    short* __restrict__ wqo, short* __restrict__ wko,
    short* __restrict__ wvo, short* __restrict__ woo)
{
    const float* src; short* dst;
    switch (blockIdx.y) {
        case 0: src = wq; dst = wqo; break;
        case 1: src = wk; dst = wko; break;
        case 2: src = wv; dst = wvo; break;
        default: src = wo; dst = woo; break;
    }
    const int n = DD * DD;
    int i = (blockIdx.x * 256 + threadIdx.x) * 8;
    const int stride = gridDim.x * 256 * 8;
    for (; i < n; i += stride) {
        fvec4 a = *(const fvec4*)&src[i];
        fvec4 b = *(const fvec4*)&src[i + 4];
        s16x8 o;
        o[0] = f2bs(a[0]); o[1] = f2bs(a[1]); o[2] = f2bs(a[2]); o[3] = f2bs(a[3]);
        o[4] = f2bs(b[0]); o[5] = f2bs(b[1]); o[6] = f2bs(b[2]); o[7] = f2bs(b[3]);
        *(s16x8*)&dst[i] = o;
    }
}

// ---------------------------------------------------------------------------
// GEMM v6 (NT), bf16 MFMA: C[M,N] = (A[M,K] * Bw[N,K]^T + bias) * oscale
// BM=128 x BN tile, BK=64, 4 waves. T2 both-sides swizzle. XCD-aware decode.
// Swapped MFMA operands; packed 8B (bf16) / 16B (fp32) stores.
// AF32: A fp32 converted during staging (r18's simple __syncthreads loop --
// r19's manual vmcnt pipeline REGRESSED per m141 sched-pinning, reverted).
// r20: QKV uses BN=64 (grid 1536 = 6 blocks/CU) to fix the grid-limited
// occupancy (was 768 = 3/CU, Occ 24%, latency-bound A-staging chain).
// BN=64, NXSH=4: QKV fused AND O-proj.
// ---------------------------------------------------------------------------
template<int BN, int NXSH, bool OUTF32, bool AF32>
__global__ __launch_bounds__(256) void gemm_nt_v2(
    const void* __restrict__ A0, const void* __restrict__ A1, const void* __restrict__ A2,
    const short* __restrict__ B0, const short* __restrict__ B1, const short* __restrict__ B2,
    const float* __restrict__ c0, const float* __restrict__ c1, const float* __restrict__ c2,
    void* __restrict__ O0, void* __restrict__ O1, void* __restrict__ O2,
    float os0, float os1, float os2,
    int ppx, int NY, int KL, int N, int K)
{
    const int d   = blockIdx.x;
    const int xcd = d & 7;
    const int s   = d >> 3;
    const int x   = s & ((1 << NXSH) - 1);
    const int pl  = s >> NXSH;
    const int panel = xcd * ppx + pl;
    const int y   = panel % NY;
    const int z   = panel / NY;

    const void* Av    = z == 0 ? A0 : (z == 1 ? A1 : A2);
    const short* Bw   = z == 0 ? B0 : (z == 1 ? B1 : B2);
    const float* bias = z == 0 ? c0 : (z == 1 ? c1 : c2);
    void* Cp          = z == 0 ? O0 : (z == 1 ? O1 : O2);
    const float oscale = z == 0 ? os0 : (z == 1 ? os1 : os2);
    const short* Ab = (const short*)Av;
    const float* Af = (const float*)Av;

    __shared__ short As[128][64];
    __shared__ short Bs[BN][64];

    const int tid  = threadIdx.x;
    const int lane = tid & 63;
    const int wid  = tid >> 6;
    const int r16  = lane & 15;
    const int g    = lane >> 4;
    const int m0   = y * 128;
    const int n0   = x * BN;
    constexpr int MR = 4;
    constexpr int NR = BN / 32;          // 128->4, 64->2
    const int wr   = (wid >> 1) * 64;
    const int wc   = (wid & 1) * (BN / 2);
    const int srow8 = lane >> 3;         // 0..7
    const int c8    = lane & 7;          // chunk 0..7

    f32x4 acc[MR][NR];
#pragma unroll
    for (int mi = 0; mi < MR; ++mi)
#pragma unroll
        for (int ni = 0; ni < NR; ++ni) acc[mi][ni] = (f32x4){0.f, 0.f, 0.f, 0.f};

    const int csrc = (c8 ^ srow8) * 8;   // source-swizzled chunk (B path)
    const int nk = KL >> 6;
#pragma unroll 1
    for (int kt = 0; kt < nk; ++kt) {
        const int k0 = kt * 64;
        if (kt) __syncthreads();
        // --- stage B (BNx64) via global_load_lds, source-swizzled ---
#pragma unroll
        for (int q = 0; q < BN / 32; ++q) {
            const int r = wid * (BN / 4) + q * 8 + srow8;
            gload_lds16(&Bw[(size_t)(n0 + r) * K + k0 + csrc], &Bs[wid * (BN / 4) + q * 8][0]);
        }
        // --- stage A (128x64) ---
        if constexpr (AF32) {
            // fp32 A: register-stage with convert; write swizzled slot directly
#pragma unroll
            for (int it = 0; it < 4; ++it) {
                const int idx = it * 256 + tid;   // 0..1023
                const int row = idx >> 3;         // 0..127
                const int ca  = idx & 7;          // chunk 0..7
                const float* srcp = &Af[(size_t)(m0 + row) * K + k0 + ca * 8];
                const fvec4 a0 = *(const fvec4*)srcp;
                const fvec4 a1 = *(const fvec4*)(srcp + 4);
                u32x4 wv_;
                wv_[0] = cvtpk(a0[0], a0[1]);
                wv_[1] = cvtpk(a0[2], a0[3]);
                wv_[2] = cvtpk(a1[0], a1[1]);
                wv_[3] = cvtpk(a1[2], a1[3]);
                *(u32x4*)&As[row][((ca ^ (row & 7)) & 7) * 8] = wv_;
            }
        } else {
#pragma unroll
            for (int q = 0; q < 4; ++q) {
                const int r = wid * 32 + q * 8 + srow8;
                gload_lds16(&Ab[(size_t)(m0 + r) * K + k0 + csrc], &As[wid * 32 + q * 8][0]);
            }
        }
        __syncthreads();   // drains vmcnt + lgkmcnt

#pragma unroll
        for (int kk = 0; kk < 2; ++kk) {
            s16x8 af[MR], bf[NR];
#pragma unroll
            for (int mi = 0; mi < MR; ++mi) {
                const int row = wr + mi * 16 + r16;
                af[mi] = *(const s16x8*)&As[row][((kk * 4 + g) ^ (row & 7)) * 8];
            }
#pragma unroll
            for (int ni = 0; ni < NR; ++ni) {
                const int row = wc + ni * 16 + r16;
                bf[ni] = *(const s16x8*)&Bs[row][((kk * 4 + g) ^ (row & 7)) * 8];
            }
            // swapped operands: lane holds row m = wr+mi*16+r16,
            // cols n = wc+ni*16+g*4+{0..3}
#pragma unroll
            for (int mi = 0; mi < MR; ++mi)
#pragma unroll
                for (int ni = 0; ni < NR; ++ni)
                    acc[mi][ni] = __builtin_amdgcn_mfma_f32_16x16x32_bf16(
                        bf[ni], af[mi], acc[mi][ni], 0, 0, 0);
        }
    }

    // epilogue: row = m0+wr+mi*16+r16; cols = n0+wc+ni*16+g*4+{0..3}
#pragma unroll
    for (int mi = 0; mi < MR; ++mi) {
        const size_t row = (size_t)(m0 + wr + mi * 16 + r16);
#pragma unroll
        for (int ni = 0; ni < NR; ++ni) {
            const int colb = n0 + wc + ni * 16 + g * 4;
            fvec4 bv;
            if (bias) bv = *(const fvec4*)&bias[colb];
            else      bv = (fvec4){0.f, 0.f, 0.f, 0.f};
            const f32x4 a = acc[mi][ni];
            const float v0 = (a[0] + bv[0]) * oscale;
            const float v1 = (a[1] + bv[1]) * oscale;
            const float v2 = (a[2] + bv[2]) * oscale;
            const float v3 = (a[3] + bv[3]) * oscale;
            if constexpr (OUTF32) {
                fvec4 o; o[0] = v0; o[1] = v1; o[2] = v2; o[3] = v3;
                *(fvec4*)&((float*)Cp)[row * N + colb] = o;
            } else {
                u32x2 w;
                w[0] = cvtpk(v0, v1);
                w[1] = cvtpk(v2, v3);
                *(u32x2*)&((short*)Cp)[row * N + colb] = w;
            }
        }
    }
}

// ---------------------------------------------------------------------------
// Per-head V transpose: vp (head-major [bh][s][dk]) -> vT ([bh][dk][s])
// ---------------------------------------------------------------------------
__global__ __launch_bounds__(256) void mha_transpose_v(
    const short* __restrict__ vp, short* __restrict__ vT)
{
    const int st = blockIdx.x;
    const int bh = blockIdx.y;
    const short* src = vp + (size_t)bh * SS * DKK;
    short*       dst = vT + (size_t)bh * SS * DKK;
    const int tid = threadIdx.x;
#pragma unroll
    for (int i = 0; i < 2; ++i) {
        const int c  = tid + i * 256;   // 0..511
        const int dk = c >> 3;          // 0..63
        const int sc = c & 7;           // 0..7
        const int s0 = st * 64 + sc * 8;
        s16x8 v;
#pragma unroll
        for (int j = 0; j < 8; ++j) v[j] = src[(size_t)(s0 + j) * DKK + dk];
        *(s16x8*)&dst[(size_t)dk * SS + s0] = v;
    }
}

// ---------------------------------------------------------------------------
// Flash attention v7 (causal) -- r15 version verbatim (proven 40.7us):
// 1024 blocks (4/CU), one 64-row q-group per block, 4 waves x 16 rows.
// Balance decode: v = (lin>>3)>>2; grp = v<16 ? v : 47-v.
// Head pinned to XCD via lin&7. Single-buffered staging.
// ---------------------------------------------------------------------------
__global__ __launch_bounds__(256, 2) void mha_attn(
    const short* __restrict__ qp, const short* __restrict__ kp,
    const short* __restrict__ vT, short* __restrict__ ctx)
{
    __shared__ short Ks[64][64];     // [key][dk]   (chunk-swizzled)
    __shared__ short Vs[64][64];     // [dv][key]   (chunk-swizzled)
    __shared__ short P[4][16][72];   // per-wave P[q][key], padded rows

    const int tid  = threadIdx.x;
    const int wid  = tid >> 6;
    const int lane = tid & 63;
    const int r16  = lane & 15;
    const int g    = lane >> 4;

    const int lin = blockIdx.x;           // 0..1023
    const int xcd = lin & 7;
    const int s8  = lin >> 3;             // 0..127
    const int bh  = (xcd << 2) | (s8 & 3);
    const int v   = s8 >> 2;              // 0..31
    const int grp = (v < 16) ? v : (47 - v);
    const int b   = bh >> 4;
    const int h   = bh & 15;

    const short* Qh = qp + (size_t)bh * SS * DKK;
    const short* Kh = kp + (size_t)bh * SS * DKK;
    const short* Vh = vT + (size_t)bh * SS * DKK;   // [DK][S]

    const int srow = lane >> 3;                     // 0..7
    const int csw  = (((lane & 7) ^ srow) & 7) * 8; // source-swizzled chunk
    const int r0   = wid * 16;                      // wave's staging stripe

    const int qr0 = grp * 64 + wid * 16;
    const int nkt = grp + 1;

    const s16x8 qf0 = *(const s16x8*)&Qh[(size_t)(qr0 + r16) * DKK + g * 8];
    const s16x8 qf1 = *(const s16x8*)&Qh[(size_t)(qr0 + r16) * DKK + 32 + g * 8];

    f32x4 po[4];
#pragma unroll
    for (int i = 0; i < 4; ++i) po[i] = (f32x4){0.f, 0.f, 0.f, 0.f};
    float lsum = 0.f;   // partial softmax denom for q = r16

#pragma unroll 1
    for (int j = 0; j < nkt; ++j) {
        const int k0 = j * 64;
        __syncthreads();   // protect Ks/Vs reuse
        {
            const int rowA = r0 + srow;
            const int rowB = rowA + 8;
            gload_lds16(&Kh[(size_t)(k0 + rowA) * DKK + csw], &Ks[r0][0]);
            gload_lds16(&Kh[(size_t)(k0 + rowB) * DKK + csw], &Ks[r0 + 8][0]);
            gload_lds16(&Vh[(size_t)rowA * SS + k0 + csw], &Vs[r0][0]);
            gload_lds16(&Vh[(size_t)rowB * SS + k0 + csw], &Vs[r0 + 8][0]);
        }
        __syncthreads();   // drain vmcnt: tiles ready

        // ---- swapped QK^T: T[key][q] = mfma(A=K, B=Q) ----
        f32x4 sc[4];
        __builtin_amdgcn_s_setprio(1);
#pragma unroll
        for (int cg = 0; cg < 4; ++cg) {
            const int R  = cg * 16 + r16;
            const int sw = R & 7;
            const s16x8 kf0 = *(const s16x8*)&Ks[R][((g ^ sw) & 7) * 8];
            const s16x8 kf1 = *(const s16x8*)&Ks[R][(((4 + g) ^ sw) & 7) * 8];
            f32x4 tt = (f32x4){0.f, 0.f, 0.f, 0.f};
            tt = __builtin_amdgcn_mfma_f32_16x16x32_bf16(kf0, qf0, tt, 0, 0, 0);
            tt = __builtin_amdgcn_mfma_f32_16x16x32_bf16(kf1, qf1, tt, 0, 0, 0);
            sc[cg] = tt;   // lane: q = r16, keys = k0 + cg*16 + g*4 + r
        }
        __builtin_amdgcn_s_setprio(0);

        // ---- causal mask (diag tile): key > q-row ----
        if (j == nkt - 1) {
#pragma unroll
            for (int cg = 0; cg < 4; ++cg)
#pragma unroll
                for (int r = 0; r < 4; ++r)
                    if (k0 + cg * 16 + g * 4 + r > qr0 + r16) sc[cg][r] = -1e9f;
        }
        // ---- softmax-lite: exp, lane-local sum, packed P write ----
#pragma unroll
        for (int cg = 0; cg < 4; ++cg) {
            const float p0 = __expf(sc[cg][0]);
            const float p1 = __expf(sc[cg][1]);
            const float p2 = __expf(sc[cg][2]);
            const float p3 = __expf(sc[cg][3]);
            lsum += (p0 + p1) + (p2 + p3);
            u32x2 w;
            w[0] = cvtpk(p0, p1);
            w[1] = cvtpk(p2, p3);
            *(u32x2*)&P[wid][r16][cg * 16 + g * 4] = w;   // ds_write_b64
        }
        // same-wave write->read: compiler inserts lgkmcnt wait
        const s16x8 pf0 = *(const s16x8*)&P[wid][r16][g * 8];
        const s16x8 pf1 = *(const s16x8*)&P[wid][r16][32 + g * 8];

        // ---- PV: A = P, B = V ----
        __builtin_amdgcn_s_setprio(1);
#pragma unroll
        for (int dg = 0; dg < 4; ++dg) {
            const int Rv = dg * 16 + r16;
            const int sw = Rv & 7;
            const s16x8 vf0 = *(const s16x8*)&Vs[Rv][((g ^ sw) & 7) * 8];
            const s16x8 vf1 = *(const s16x8*)&Vs[Rv][(((4 + g) ^ sw) & 7) * 8];
            po[dg] = __builtin_amdgcn_mfma_f32_16x16x32_bf16(pf0, vf0, po[dg], 0, 0, 0);
            po[dg] = __builtin_amdgcn_mfma_f32_16x16x32_bf16(pf1, vf1, po[dg], 0, 0, 0);
        }
        __builtin_amdgcn_s_setprio(0);
    }

    // ---- epilogue: finish denom, fetch per-row inverse, store ----
    lsum += __shfl_xor(lsum, 16);
    lsum += __shfl_xor(lsum, 32);   // lane now holds total for q = r16
    const float linv = __builtin_amdgcn_rcpf(lsum);
    float rowinv[4];
#pragma unroll
    for (int r = 0; r < 4; ++r)
        rowinv[r] = __shfl(linv, g * 4 + r);   // lane (g*4+r) has q = g*4+r
#pragma unroll
    for (int dg = 0; dg < 4; ++dg)
#pragma unroll
        for (int r = 0; r < 4; ++r) {
            const int srw = qr0 + g * 4 + r;
            const float vv = po[dg][r] * rowinv[r];
            ctx[((size_t)(b * SS + srw)) * DD + h * 64 + dg * 16 + r16] = f2bs(vv);
        }
}

// ---------------------------------------------------------------------------
extern "C" void kernel_launch(void* const* d_in, const int* in_sizes, int n_in,
                              void* d_out, int out_size, void* d_ws, size_t ws_size,
                              hipStream_t stream) {
    const float* query = (const float*)d_in[0];
    const float* key   = (const float*)d_in[1];
    const float* value = (const float*)d_in[2];
    // d_in[3] = mask (causal tril) -- implemented analytically
    const float* Wq = (const float*)d_in[4];
    const float* bq = (const float*)d_in[5];
    const float* Wk = (const float*)d_in[6];
    const float* bk = (const float*)d_in[7];
    const float* Wv = (const float*)d_in[8];
    const float* bv = (const float*)d_in[9];
    const float* Wo = (const float*)d_in[10];
    const float* bo = (const float*)d_in[11];
    float* out = (float*)d_out;

    const size_t elems = (size_t)BB * SS * DD;   // 4M
    const size_t wel   = (size_t)DD * DD;        // 1M
    short* wqx = (short*)d_ws;        // bf16 weights (8 MB)
    short* wkx = wqx + wel;
    short* wvx = wkx + wel;
    short* wox = wvx + wel;
    short* qp  = wox + wel;           // projections (24 MB)
    short* kp  = qp + elems;
    short* vp  = kp + elems;
    short* vT  = vp + elems;          // transposed V (8 MB)
    short* ctx = vT + elems;          // attention output (8 MB) -- 48 MB total

    // 1) convert weights to bf16 (24 MB traffic)
    cvt_w<<<dim3(512, 4), 256, 0, stream>>>(Wq, Wk, Wv, Wo, wqx, wkx, wvx, wox);
    // 2) fused Q/K/V projections; A = fp32 inputs converted during staging
    //    (r18 loop); BN=64 -> 1536 blocks = 6/CU for occupancy; 1/sqrt(DK)
    //    folded into Q
    gemm_nt_v2<64, 4, false, true><<<dim3(1536), 256, 0, stream>>>(
        query, key, value, wqx, wkx, wvx, bq, bk, bv, qp, kp, vp,
        0.125f, 1.0f, 1.0f, /*ppx=*/12, /*NY=*/32, /*KL=*/1024, DD, DD);
    // 3) V transpose per head
    mha_transpose_v<<<dim3(SS / 64, BB * HH), 256, 0, stream>>>(vp, vT);
    // 4) attention -> ctx: r15 structure (proven 40.7us)
    mha_attn<<<dim3(1024), 256, 0, stream>>>(qp, kp, vT, ctx);
    // 5) output projection, direct (BM=128, BN=64 -> 512 blocks = 2/CU)
    gemm_nt_v2<64, 4, true, false><<<dim3(512), 256, 0, stream>>>(
        ctx, ctx, ctx, wox, wox, wox, bo, bo, bo, out, out, out,
        1.0f, 1.0f, 1.0f, /*ppx=*/4, /*NY=*/32, /*KL=*/1024, DD, DD);
}

// Round 21
// 112.353 us; speedup vs baseline: 1.2397x; 1.2397x over previous
//
#include <hip/hip_runtime.h>
#include <hip/hip_bf16.h>

// Problem constants
#define BB 2
#define SS 2048
#define DD 1024
#define HH 16
#define DKK 64

typedef __attribute__((ext_vector_type(4))) float  f32x4;
typedef __attribute__((ext_vector_type(8))) short  s16x8;
typedef __attribute__((ext_vector_type(4))) short  s16x4;
typedef __attribute__((ext_vector_type(4))) float  fvec4;
typedef __attribute__((ext_vector_type(2))) unsigned int u32x2;
typedef __attribute__((ext_vector_type(4))) unsigned int u32x4;

__device__ __forceinline__ short f2bs(float f) {
    union { __hip_bfloat16 b; short s; } u;
    u.b = __float2bfloat16(f);
    return u.s;
}

// pack two f32 -> u32 of two bf16 (v_cvt_pk_bf16_f32; no builtin on gfx950)
__device__ __forceinline__ unsigned cvtpk(float lo, float hi) {
    unsigned r;
    asm("v_cvt_pk_bf16_f32 %0, %1, %2" : "=v"(r) : "v"(lo), "v"(hi));
    return r;
}

__device__ __forceinline__ void gload_lds16(const short* g, short* l) {
    __builtin_amdgcn_global_load_lds((const __attribute__((address_space(1))) void*)g,
                                     (__attribute__((address_space(3))) void*)l, 16, 0, 0);
}

// ---------------------------------------------------------------------------
// fp32 -> bf16 convert, WEIGHTS ONLY (24 MB traffic; q/k/v conversion is
// fused into the QKV GEMM's A-staging)
// ---------------------------------------------------------------------------
__global__ __launch_bounds__(256) void cvt_w(
    const float* __restrict__ wq, const float* __restrict__ wk,
    const float* __restrict__ wv, const float* __restrict__ wo,
    short* __restrict__ wqo, short* __restrict__ wko,
    short* __restrict__ wvo, short* __restrict__ woo)
{
    const float* src; short* dst;
    switch (blockIdx.y) {
        case 0: src = wq; dst = wqo; break;
        case 1: src = wk; dst = wko; break;
        case 2: src = wv; dst = wvo; break;
        default: src = wo; dst = woo; break;
    }
    const int n = DD * DD;
    int i = (blockIdx.x * 256 + threadIdx.x) * 8;
    const int stride = gridDim.x * 256 * 8;
    for (; i < n; i += stride) {
        fvec4 a = *(const fvec4*)&src[i];
        fvec4 b = *(const fvec4*)&src[i + 4];
        s16x8 o;
        o[0] = f2bs(a[0]); o[1] = f2bs(a[1]); o[2] = f2bs(a[2]); o[3] = f2bs(a[3]);
        o[4] = f2bs(b[0]); o[5] = f2bs(b[1]); o[6] = f2bs(b[2]); o[7] = f2bs(b[3]);
        *(s16x8*)&dst[i] = o;
    }
}

// ---------------------------------------------------------------------------
// GEMM v7 (NT), bf16 MFMA: C[M,N] = (A[M,K] * Bw[N,K]^T + bias) * oscale
// BMxBN tile, BK=64, 4 waves (wave does (BM/2)x(BN/2)). T2 both-sides
// swizzle; XCD-aware decode; swapped MFMA operands; packed stores.
// AF32 (BM=128 only): A fp32 converted during staging (r18 loop -- manual
// pipelining regressed twice, r19/m141; BN=64-QKV regressed, r20: A-convert
// is per-block fixed cost, don't duplicate it).
// QKV: BM=128,BN=128 (768 blocks). O-proj: BM=64,BN=64 (1024 blocks = 4/CU,
// r21 change -- was BM=128,BN=64 at 2/CU, occupancy-limited ~22us).
// ---------------------------------------------------------------------------
template<int BM, int BN, int NXSH, bool OUTF32, bool AF32>
__global__ __launch_bounds__(256) void gemm_nt_v2(
    const void* __restrict__ A0, const void* __restrict__ A1, const void* __restrict__ A2,
    const short* __restrict__ B0, const short* __restrict__ B1, const short* __restrict__ B2,
    const float* __restrict__ c0, const float* __restrict__ c1, const float* __restrict__ c2,
    void* __restrict__ O0, void* __restrict__ O1, void* __restrict__ O2,
    float os0, float os1, float os2,
    int ppx, int NY, int KL, int N, int K)
{
    const int d   = blockIdx.x;
    const int xcd = d & 7;
    const int s   = d >> 3;
    const int x   = s & ((1 << NXSH) - 1);
    const int pl  = s >> NXSH;
    const int panel = xcd * ppx + pl;
    const int y   = panel % NY;
    const int z   = panel / NY;

    const void* Av    = z == 0 ? A0 : (z == 1 ? A1 : A2);
    const short* Bw   = z == 0 ? B0 : (z == 1 ? B1 : B2);
    const float* bias = z == 0 ? c0 : (z == 1 ? c1 : c2);
    void* Cp          = z == 0 ? O0 : (z == 1 ? O1 : O2);
    const float oscale = z == 0 ? os0 : (z == 1 ? os1 : os2);
    const short* Ab = (const short*)Av;
    const float* Af = (const float*)Av;

    __shared__ short As[BM][64];
    __shared__ short Bs[BN][64];

    const int tid  = threadIdx.x;
    const int lane = tid & 63;
    const int wid  = tid >> 6;
    const int r16  = lane & 15;
    const int g    = lane >> 4;
    const int m0   = y * BM;
    const int n0   = x * BN;
    constexpr int MR = BM / 32;
    constexpr int NR = BN / 32;
    const int wr   = (wid >> 1) * (BM / 2);
    const int wc   = (wid & 1) * (BN / 2);
    const int srow8 = lane >> 3;         // 0..7
    const int c8    = lane & 7;          // chunk 0..7

    f32x4 acc[MR][NR];
#pragma unroll
    for (int mi = 0; mi < MR; ++mi)
#pragma unroll
        for (int ni = 0; ni < NR; ++ni) acc[mi][ni] = (f32x4){0.f, 0.f, 0.f, 0.f};

    const int csrc = (c8 ^ srow8) * 8;   // source-swizzled chunk
    const int nk = KL >> 6;
#pragma unroll 1
    for (int kt = 0; kt < nk; ++kt) {
        const int k0 = kt * 64;
        if (kt) __syncthreads();
        // --- stage B (BNx64) via global_load_lds, source-swizzled ---
#pragma unroll
        for (int q = 0; q < BN / 32; ++q) {
            const int r = wid * (BN / 4) + q * 8 + srow8;
            gload_lds16(&Bw[(size_t)(n0 + r) * K + k0 + csrc], &Bs[wid * (BN / 4) + q * 8][0]);
        }
        // --- stage A (BMx64) ---
        if constexpr (AF32) {
            // fp32 A (BM=128): register-stage with convert, swizzled write
#pragma unroll
            for (int it = 0; it < 4; ++it) {
                const int idx = it * 256 + tid;   // 0..1023
                const int row = idx >> 3;         // 0..127
                const int ca  = idx & 7;          // chunk 0..7
                const float* srcp = &Af[(size_t)(m0 + row) * K + k0 + ca * 8];
                const fvec4 a0 = *(const fvec4*)srcp;
                const fvec4 a1 = *(const fvec4*)(srcp + 4);
                u32x4 wv_;
                wv_[0] = cvtpk(a0[0], a0[1]);
                wv_[1] = cvtpk(a0[2], a0[3]);
                wv_[2] = cvtpk(a1[0], a1[1]);
                wv_[3] = cvtpk(a1[2], a1[3]);
                *(u32x4*)&As[row][((ca ^ (row & 7)) & 7) * 8] = wv_;
            }
        } else {
#pragma unroll
            for (int q = 0; q < BM / 32; ++q) {
                const int r = wid * (BM / 4) + q * 8 + srow8;
                gload_lds16(&Ab[(size_t)(m0 + r) * K + k0 + csrc], &As[wid * (BM / 4) + q * 8][0]);
            }
        }
        __syncthreads();   // drains vmcnt + lgkmcnt

#pragma unroll
        for (int kk = 0; kk < 2; ++kk) {
            s16x8 af[MR], bf[NR];
#pragma unroll
            for (int mi = 0; mi < MR; ++mi) {
                const int row = wr + mi * 16 + r16;
                af[mi] = *(const s16x8*)&As[row][((kk * 4 + g) ^ (row & 7)) * 8];
            }
#pragma unroll
            for (int ni = 0; ni < NR; ++ni) {
                const int row = wc + ni * 16 + r16;
                bf[ni] = *(const s16x8*)&Bs[row][((kk * 4 + g) ^ (row & 7)) * 8];
            }
            // swapped operands: lane holds row m = wr+mi*16+r16,
            // cols n = wc+ni*16+g*4+{0..3}
#pragma unroll
            for (int mi = 0; mi < MR; ++mi)
#pragma unroll
                for (int ni = 0; ni < NR; ++ni)
                    acc[mi][ni] = __builtin_amdgcn_mfma_f32_16x16x32_bf16(
                        bf[ni], af[mi], acc[mi][ni], 0, 0, 0);
        }
    }

    // epilogue: row = m0+wr+mi*16+r16; cols = n0+wc+ni*16+g*4+{0..3}
#pragma unroll
    for (int mi = 0; mi < MR; ++mi) {
        const size_t row = (size_t)(m0 + wr + mi * 16 + r16);
#pragma unroll
        for (int ni = 0; ni < NR; ++ni) {
            const int colb = n0 + wc + ni * 16 + g * 4;
            fvec4 bv;
            if (bias) bv = *(const fvec4*)&bias[colb];
            else      bv = (fvec4){0.f, 0.f, 0.f, 0.f};
            const f32x4 a = acc[mi][ni];
            const float v0 = (a[0] + bv[0]) * oscale;
            const float v1 = (a[1] + bv[1]) * oscale;
            const float v2 = (a[2] + bv[2]) * oscale;
            const float v3 = (a[3] + bv[3]) * oscale;
            if constexpr (OUTF32) {
                fvec4 o; o[0] = v0; o[1] = v1; o[2] = v2; o[3] = v3;
                *(fvec4*)&((float*)Cp)[row * N + colb] = o;
            } else {
                u32x2 w;
                w[0] = cvtpk(v0, v1);
                w[1] = cvtpk(v2, v3);
                *(u32x2*)&((short*)Cp)[row * N + colb] = w;
            }
        }
    }
}

// ---------------------------------------------------------------------------
// Per-head V transpose: vp (head-major [bh][s][dk]) -> vT ([bh][dk][s])
// ---------------------------------------------------------------------------
__global__ __launch_bounds__(256) void mha_transpose_v(
    const short* __restrict__ vp, short* __restrict__ vT)
{
    const int st = blockIdx.x;
    const int bh = blockIdx.y;
    const short* src = vp + (size_t)bh * SS * DKK;
    short*       dst = vT + (size_t)bh * SS * DKK;
    const int tid = threadIdx.x;
#pragma unroll
    for (int i = 0; i < 2; ++i) {
        const int c  = tid + i * 256;   // 0..511
        const int dk = c >> 3;          // 0..63
        const int sc = c & 7;           // 0..7
        const int s0 = st * 64 + sc * 8;
        s16x8 v;
#pragma unroll
        for (int j = 0; j < 8; ++j) v[j] = src[(size_t)(s0 + j) * DKK + dk];
        *(s16x8*)&dst[(size_t)dk * SS + s0] = v;
    }
}

// ---------------------------------------------------------------------------
// Flash attention v7 (causal) -- r15 version verbatim (proven 40.7us):
// 1024 blocks (4/CU), one 64-row q-group per block, 4 waves x 16 rows.
// Balance decode: v = (lin>>3)>>2; grp = v<16 ? v : 47-v.
// Head pinned to XCD via lin&7. Single-buffered staging.
// ---------------------------------------------------------------------------
__global__ __launch_bounds__(256, 2) void mha_attn(
    const short* __restrict__ qp, const short* __restrict__ kp,
    const short* __restrict__ vT, short* __restrict__ ctx)
{
    __shared__ short Ks[64][64];     // [key][dk]   (chunk-swizzled)
    __shared__ short Vs[64][64];     // [dv][key]   (chunk-swizzled)
    __shared__ short P[4][16][72];   // per-wave P[q][key], padded rows

    const int tid  = threadIdx.x;
    const int wid  = tid >> 6;
    const int lane = tid & 63;
    const int r16  = lane & 15;
    const int g    = lane >> 4;

    const int lin = blockIdx.x;           // 0..1023
    const int xcd = lin & 7;
    const int s8  = lin >> 3;             // 0..127
    const int bh  = (xcd << 2) | (s8 & 3);
    const int v   = s8 >> 2;              // 0..31
    const int grp = (v < 16) ? v : (47 - v);
    const int b   = bh >> 4;
    const int h   = bh & 15;

    const short* Qh = qp + (size_t)bh * SS * DKK;
    const short* Kh = kp + (size_t)bh * SS * DKK;
    const short* Vh = vT + (size_t)bh * SS * DKK;   // [DK][S]

    const int srow = lane >> 3;                     // 0..7
    const int csw  = (((lane & 7) ^ srow) & 7) * 8; // source-swizzled chunk
    const int r0   = wid * 16;                      // wave's staging stripe

    const int qr0 = grp * 64 + wid * 16;
    const int nkt = grp + 1;

    const s16x8 qf0 = *(const s16x8*)&Qh[(size_t)(qr0 + r16) * DKK + g * 8];
    const s16x8 qf1 = *(const s16x8*)&Qh[(size_t)(qr0 + r16) * DKK + 32 + g * 8];

    f32x4 po[4];
#pragma unroll
    for (int i = 0; i < 4; ++i) po[i] = (f32x4){0.f, 0.f, 0.f, 0.f};
    float lsum = 0.f;   // partial softmax denom for q = r16

#pragma unroll 1
    for (int j = 0; j < nkt; ++j) {
        const int k0 = j * 64;
        __syncthreads();   // protect Ks/Vs reuse
        {
            const int rowA = r0 + srow;
            const int rowB = rowA + 8;
            gload_lds16(&Kh[(size_t)(k0 + rowA) * DKK + csw], &Ks[r0][0]);
            gload_lds16(&Kh[(size_t)(k0 + rowB) * DKK + csw], &Ks[r0 + 8][0]);
            gload_lds16(&Vh[(size_t)rowA * SS + k0 + csw], &Vs[r0][0]);
            gload_lds16(&Vh[(size_t)rowB * SS + k0 + csw], &Vs[r0 + 8][0]);
        }
        __syncthreads();   // drain vmcnt: tiles ready

        // ---- swapped QK^T: T[key][q] = mfma(A=K, B=Q) ----
        f32x4 sc[4];
        __builtin_amdgcn_s_setprio(1);
#pragma unroll
        for (int cg = 0; cg < 4; ++cg) {
            const int R  = cg * 16 + r16;
            const int sw = R & 7;
            const s16x8 kf0 = *(const s16x8*)&Ks[R][((g ^ sw) & 7) * 8];
            const s16x8 kf1 = *(const s16x8*)&Ks[R][(((4 + g) ^ sw) & 7) * 8];
            f32x4 tt = (f32x4){0.f, 0.f, 0.f, 0.f};
            tt = __builtin_amdgcn_mfma_f32_16x16x32_bf16(kf0, qf0, tt, 0, 0, 0);
            tt = __builtin_amdgcn_mfma_f32_16x16x32_bf16(kf1, qf1, tt, 0, 0, 0);
            sc[cg] = tt;   // lane: q = r16, keys = k0 + cg*16 + g*4 + r
        }
        __builtin_amdgcn_s_setprio(0);

        // ---- causal mask (diag tile): key > q-row ----
        if (j == nkt - 1) {
#pragma unroll
            for (int cg = 0; cg < 4; ++cg)
#pragma unroll
                for (int r = 0; r < 4; ++r)
                    if (k0 + cg * 16 + g * 4 + r > qr0 + r16) sc[cg][r] = -1e9f;
        }
        // ---- softmax-lite: exp, lane-local sum, packed P write ----
#pragma unroll
        for (int cg = 0; cg < 4; ++cg) {
            const float p0 = __expf(sc[cg][0]);
            const float p1 = __expf(sc[cg][1]);
            const float p2 = __expf(sc[cg][2]);
            const float p3 = __expf(sc[cg][3]);
            lsum += (p0 + p1) + (p2 + p3);
            u32x2 w;
            w[0] = cvtpk(p0, p1);
            w[1] = cvtpk(p2, p3);
            *(u32x2*)&P[wid][r16][cg * 16 + g * 4] = w;   // ds_write_b64
        }
        // same-wave write->read: compiler inserts lgkmcnt wait
        const s16x8 pf0 = *(const s16x8*)&P[wid][r16][g * 8];
        const s16x8 pf1 = *(const s16x8*)&P[wid][r16][32 + g * 8];

        // ---- PV: A = P, B = V ----
        __builtin_amdgcn_s_setprio(1);
#pragma unroll
        for (int dg = 0; dg < 4; ++dg) {
            const int Rv = dg * 16 + r16;
            const int sw = Rv & 7;
            const s16x8 vf0 = *(const s16x8*)&Vs[Rv][((g ^ sw) & 7) * 8];
            const s16x8 vf1 = *(const s16x8*)&Vs[Rv][(((4 + g) ^ sw) & 7) * 8];
            po[dg] = __builtin_amdgcn_mfma_f32_16x16x32_bf16(pf0, vf0, po[dg], 0, 0, 0);
            po[dg] = __builtin_amdgcn_mfma_f32_16x16x32_bf16(pf1, vf1, po[dg], 0, 0, 0);
        }
        __builtin_amdgcn_s_setprio(0);
    }

    // ---- epilogue: finish denom, fetch per-row inverse, store ----
    lsum += __shfl_xor(lsum, 16);
    lsum += __shfl_xor(lsum, 32);   // lane now holds total for q = r16
    const float linv = __builtin_amdgcn_rcpf(lsum);
    float rowinv[4];
#pragma unroll
    for (int r = 0; r < 4; ++r)
        rowinv[r] = __shfl(linv, g * 4 + r);   // lane (g*4+r) has q = g*4+r
#pragma unroll
    for (int dg = 0; dg < 4; ++dg)
#pragma unroll
        for (int r = 0; r < 4; ++r) {
            const int srw = qr0 + g * 4 + r;
            const float vv = po[dg][r] * rowinv[r];
            ctx[((size_t)(b * SS + srw)) * DD + h * 64 + dg * 16 + r16] = f2bs(vv);
        }
}

// ---------------------------------------------------------------------------
extern "C" void kernel_launch(void* const* d_in, const int* in_sizes, int n_in,
                              void* d_out, int out_size, void* d_ws, size_t ws_size,
                              hipStream_t stream) {
    const float* query = (const float*)d_in[0];
    const float* key   = (const float*)d_in[1];
    const float* value = (const float*)d_in[2];
    // d_in[3] = mask (causal tril) -- implemented analytically
    const float* Wq = (const float*)d_in[4];
    const float* bq = (const float*)d_in[5];
    const float* Wk = (const float*)d_in[6];
    const float* bk = (const float*)d_in[7];
    const float* Wv = (const float*)d_in[8];
    const float* bv = (const float*)d_in[9];
    const float* Wo = (const float*)d_in[10];
    const float* bo = (const float*)d_in[11];
    float* out = (float*)d_out;

    const size_t elems = (size_t)BB * SS * DD;   // 4M
    const size_t wel   = (size_t)DD * DD;        // 1M
    short* wqx = (short*)d_ws;        // bf16 weights (8 MB)
    short* wkx = wqx + wel;
    short* wvx = wkx + wel;
    short* wox = wvx + wel;
    short* qp  = wox + wel;           // projections (24 MB)
    short* kp  = qp + elems;
    short* vp  = kp + elems;
    short* vT  = vp + elems;          // transposed V (8 MB)
    short* ctx = vT + elems;          // attention output (8 MB) -- 48 MB total

    // 1) convert weights to bf16 (24 MB traffic)
    cvt_w<<<dim3(512, 4), 256, 0, stream>>>(Wq, Wk, Wv, Wo, wqx, wkx, wvx, wox);
    // 2) fused Q/K/V projections (r18 config: BM=128, BN=128, 768 blocks);
    //    A = fp32 inputs converted during staging; 1/sqrt(DK) folded into Q
    gemm_nt_v2<128, 128, 3, false, true><<<dim3(768), 256, 0, stream>>>(
        query, key, value, wqx, wkx, wvx, bq, bk, bv, qp, kp, vp,
        0.125f, 1.0f, 1.0f, /*ppx=*/12, /*NY=*/32, /*KL=*/1024, DD, DD);
    // 3) V transpose per head
    mha_transpose_v<<<dim3(SS / 64, BB * HH), 256, 0, stream>>>(vp, vT);
    // 4) attention -> ctx: r15 structure (proven 40.7us)
    mha_attn<<<dim3(1024), 256, 0, stream>>>(qp, kp, vT, ctx);
    // 5) output projection: BM=64, BN=64 -> 1024 blocks = 4/CU (r21 change)
    gemm_nt_v2<64, 64, 4, true, false><<<dim3(1024), 256, 0, stream>>>(
        ctx, ctx, ctx, wox, wox, wox, bo, bo, bo, out, out, out,
        1.0f, 1.0f, 1.0f, /*ppx=*/8, /*NY=*/64, /*KL=*/1024, DD, DD);
}

// Round 22
// 109.914 us; speedup vs baseline: 1.2672x; 1.0222x over previous
//
#include <hip/hip_runtime.h>
#include <hip/hip_bf16.h>

// Problem constants
#define BB 2
#define SS 2048
#define DD 1024
#define HH 16
#define DKK 64

typedef __attribute__((ext_vector_type(4))) float  f32x4;
typedef __attribute__((ext_vector_type(8))) short  s16x8;
typedef __attribute__((ext_vector_type(4))) short  s16x4;
typedef __attribute__((ext_vector_type(4))) float  fvec4;
typedef __attribute__((ext_vector_type(2))) unsigned int u32x2;
typedef __attribute__((ext_vector_type(4))) unsigned int u32x4;

__device__ __forceinline__ short f2bs(float f) {
    union { __hip_bfloat16 b; short s; } u;
    u.b = __float2bfloat16(f);
    return u.s;
}

// pack two f32 -> u32 of two bf16 (v_cvt_pk_bf16_f32; no builtin on gfx950)
__device__ __forceinline__ unsigned cvtpk(float lo, float hi) {
    unsigned r;
    asm("v_cvt_pk_bf16_f32 %0, %1, %2" : "=v"(r) : "v"(lo), "v"(hi));
    return r;
}

__device__ __forceinline__ void gload_lds16(const short* g, short* l) {
    __builtin_amdgcn_global_load_lds((const __attribute__((address_space(1))) void*)g,
                                     (__attribute__((address_space(3))) void*)l, 16, 0, 0);
}

// ---------------------------------------------------------------------------
// fp32 -> bf16 convert, WEIGHTS ONLY (24 MB traffic; q/k/v conversion is
// fused into the QKV GEMM's A-staging)
// ---------------------------------------------------------------------------
__global__ __launch_bounds__(256) void cvt_w(
    const float* __restrict__ wq, const float* __restrict__ wk,
    const float* __restrict__ wv, const float* __restrict__ wo,
    short* __restrict__ wqo, short* __restrict__ wko,
    short* __restrict__ wvo, short* __restrict__ woo)
{
    const float* src; short* dst;
    switch (blockIdx.y) {
        case 0: src = wq; dst = wqo; break;
        case 1: src = wk; dst = wko; break;
        case 2: src = wv; dst = wvo; break;
        default: src = wo; dst = woo; break;
    }
    const int n = DD * DD;
    int i = (blockIdx.x * 256 + threadIdx.x) * 8;
    const int stride = gridDim.x * 256 * 8;
    for (; i < n; i += stride) {
        fvec4 a = *(const fvec4*)&src[i];
        fvec4 b = *(const fvec4*)&src[i + 4];
        s16x8 o;
        o[0] = f2bs(a[0]); o[1] = f2bs(a[1]); o[2] = f2bs(a[2]); o[3] = f2bs(a[3]);
        o[4] = f2bs(b[0]); o[5] = f2bs(b[1]); o[6] = f2bs(b[2]); o[7] = f2bs(b[3]);
        *(s16x8*)&dst[i] = o;
    }
}

// ---------------------------------------------------------------------------
// GEMM v7 (NT), bf16 MFMA: C[M,N] = (A[M,K] * Bw[N,K]^T + bias) * oscale
// BMxBN tile, BK=64, 4 waves (wave does (BM/2)x(BN/2)). T2 both-sides
// swizzle; XCD-aware decode; swapped MFMA operands; packed stores.
// AF32 (BM=128 only): A fp32 converted during staging.
// QKV: BM=128,BN=128 (768 blocks). O-proj: BM=64,BN=64 (1024 blocks = 4/CU).
// ---------------------------------------------------------------------------
template<int BM, int BN, int NXSH, bool OUTF32, bool AF32>
__global__ __launch_bounds__(256) void gemm_nt_v2(
    const void* __restrict__ A0, const void* __restrict__ A1, const void* __restrict__ A2,
    const short* __restrict__ B0, const short* __restrict__ B1, const short* __restrict__ B2,
    const float* __restrict__ c0, const float* __restrict__ c1, const float* __restrict__ c2,
    void* __restrict__ O0, void* __restrict__ O1, void* __restrict__ O2,
    float os0, float os1, float os2,
    int ppx, int NY, int KL, int N, int K)
{
    const int d   = blockIdx.x;
    const int xcd = d & 7;
    const int s   = d >> 3;
    const int x   = s & ((1 << NXSH) - 1);
    const int pl  = s >> NXSH;
    const int panel = xcd * ppx + pl;
    const int y   = panel % NY;
    const int z   = panel / NY;

    const void* Av    = z == 0 ? A0 : (z == 1 ? A1 : A2);
    const short* Bw   = z == 0 ? B0 : (z == 1 ? B1 : B2);
    const float* bias = z == 0 ? c0 : (z == 1 ? c1 : c2);
    void* Cp          = z == 0 ? O0 : (z == 1 ? O1 : O2);
    const float oscale = z == 0 ? os0 : (z == 1 ? os1 : os2);
    const short* Ab = (const short*)Av;
    const float* Af = (const float*)Av;

    __shared__ short As[BM][64];
    __shared__ short Bs[BN][64];

    const int tid  = threadIdx.x;
    const int lane = tid & 63;
    const int wid  = tid >> 6;
    const int r16  = lane & 15;
    const int g    = lane >> 4;
    const int m0   = y * BM;
    const int n0   = x * BN;
    constexpr int MR = BM / 32;
    constexpr int NR = BN / 32;
    const int wr   = (wid >> 1) * (BM / 2);
    const int wc   = (wid & 1) * (BN / 2);
    const int srow8 = lane >> 3;         // 0..7
    const int c8    = lane & 7;          // chunk 0..7

    f32x4 acc[MR][NR];
#pragma unroll
    for (int mi = 0; mi < MR; ++mi)
#pragma unroll
        for (int ni = 0; ni < NR; ++ni) acc[mi][ni] = (f32x4){0.f, 0.f, 0.f, 0.f};

    const int csrc = (c8 ^ srow8) * 8;   // source-swizzled chunk
    const int nk = KL >> 6;
#pragma unroll 1
    for (int kt = 0; kt < nk; ++kt) {
        const int k0 = kt * 64;
        if (kt) __syncthreads();
        // --- stage B (BNx64) via global_load_lds, source-swizzled ---
#pragma unroll
        for (int q = 0; q < BN / 32; ++q) {
            const int r = wid * (BN / 4) + q * 8 + srow8;
            gload_lds16(&Bw[(size_t)(n0 + r) * K + k0 + csrc], &Bs[wid * (BN / 4) + q * 8][0]);
        }
        // --- stage A (BMx64) ---
        if constexpr (AF32) {
            // fp32 A (BM=128): register-stage with convert, swizzled write
#pragma unroll
            for (int it = 0; it < 4; ++it) {
                const int idx = it * 256 + tid;   // 0..1023
                const int row = idx >> 3;         // 0..127
                const int ca  = idx & 7;          // chunk 0..7
                const float* srcp = &Af[(size_t)(m0 + row) * K + k0 + ca * 8];
                const fvec4 a0 = *(const fvec4*)srcp;
                const fvec4 a1 = *(const fvec4*)(srcp + 4);
                u32x4 wv_;
                wv_[0] = cvtpk(a0[0], a0[1]);
                wv_[1] = cvtpk(a0[2], a0[3]);
                wv_[2] = cvtpk(a1[0], a1[1]);
                wv_[3] = cvtpk(a1[2], a1[3]);
                *(u32x4*)&As[row][((ca ^ (row & 7)) & 7) * 8] = wv_;
            }
        } else {
#pragma unroll
            for (int q = 0; q < BM / 32; ++q) {
                const int r = wid * (BM / 4) + q * 8 + srow8;
                gload_lds16(&Ab[(size_t)(m0 + r) * K + k0 + csrc], &As[wid * (BM / 4) + q * 8][0]);
            }
        }
        __syncthreads();   // drains vmcnt + lgkmcnt

#pragma unroll
        for (int kk = 0; kk < 2; ++kk) {
            s16x8 af[MR], bf[NR];
#pragma unroll
            for (int mi = 0; mi < MR; ++mi) {
                const int row = wr + mi * 16 + r16;
                af[mi] = *(const s16x8*)&As[row][((kk * 4 + g) ^ (row & 7)) * 8];
            }
#pragma unroll
            for (int ni = 0; ni < NR; ++ni) {
                const int row = wc + ni * 16 + r16;
                bf[ni] = *(const s16x8*)&Bs[row][((kk * 4 + g) ^ (row & 7)) * 8];
            }
            // swapped operands: lane holds row m = wr+mi*16+r16,
            // cols n = wc+ni*16+g*4+{0..3}
#pragma unroll
            for (int mi = 0; mi < MR; ++mi)
#pragma unroll
                for (int ni = 0; ni < NR; ++ni)
                    acc[mi][ni] = __builtin_amdgcn_mfma_f32_16x16x32_bf16(
                        bf[ni], af[mi], acc[mi][ni], 0, 0, 0);
        }
    }

    // epilogue: row = m0+wr+mi*16+r16; cols = n0+wc+ni*16+g*4+{0..3}
#pragma unroll
    for (int mi = 0; mi < MR; ++mi) {
        const size_t row = (size_t)(m0 + wr + mi * 16 + r16);
#pragma unroll
        for (int ni = 0; ni < NR; ++ni) {
            const int colb = n0 + wc + ni * 16 + g * 4;
            fvec4 bv;
            if (bias) bv = *(const fvec4*)&bias[colb];
            else      bv = (fvec4){0.f, 0.f, 0.f, 0.f};
            const f32x4 a = acc[mi][ni];
            const float v0 = (a[0] + bv[0]) * oscale;
            const float v1 = (a[1] + bv[1]) * oscale;
            const float v2 = (a[2] + bv[2]) * oscale;
            const float v3 = (a[3] + bv[3]) * oscale;
            if constexpr (OUTF32) {
                fvec4 o; o[0] = v0; o[1] = v1; o[2] = v2; o[3] = v3;
                *(fvec4*)&((float*)Cp)[row * N + colb] = o;
            } else {
                u32x2 w;
                w[0] = cvtpk(v0, v1);
                w[1] = cvtpk(v2, v3);
                *(u32x2*)&((short*)Cp)[row * N + colb] = w;
            }
        }
    }
}

// ---------------------------------------------------------------------------
// Per-head V transpose v2: vp ([bh][s][dk]) -> vT ([bh][dk][s]).
// r22: LDS-tiled -- the old version's global reads were 8 scalar 2B loads
// at 1KB stride (16x segment amplification). Now: coalesced 16B/lane reads
// into a padded LDS tile (stride 66 shorts: phase-2 column reads spread
// over 16 banks, ~2-way = free), coalesced 16B/lane writes.
// ---------------------------------------------------------------------------
__global__ __launch_bounds__(256) void mha_transpose_v(
    const short* __restrict__ vp, short* __restrict__ vT)
{
    __shared__ short T[64][66];
    const int st = blockIdx.x;
    const int bh = blockIdx.y;
    const short* src = vp + (size_t)bh * SS * DKK + (size_t)st * 64 * DKK;
    short*       dst = vT + (size_t)bh * SS * DKK + st * 64;
    const int tid = threadIdx.x;
    const int row = tid >> 3;        // 0..31
    const int ch  = tid & 7;         // 0..7
    // phase 1: coalesced reads of V rows (s-major), 16B per lane
#pragma unroll
    for (int i = 0; i < 2; ++i) {
        const int r = row + i * 32;
        *(s16x8*)&T[r][ch * 8] = *(const s16x8*)&src[(size_t)r * DKK + ch * 8];
    }
    __syncthreads();
    // phase 2: gather columns from LDS, coalesced 16B writes of vT rows
#pragma unroll
    for (int i = 0; i < 2; ++i) {
        const int dk = row + i * 32;
        s16x8 v;
#pragma unroll
        for (int j = 0; j < 8; ++j) v[j] = T[ch * 8 + j][dk];
        *(s16x8*)&dst[(size_t)dk * SS + ch * 8] = v;
    }
}

// ---------------------------------------------------------------------------
// Flash attention v7 (causal) -- r15 version verbatim (proven 40.7us):
// 1024 blocks (4/CU), one 64-row q-group per block, 4 waves x 16 rows.
// Balance decode: v = (lin>>3)>>2; grp = v<16 ? v : 47-v.
// Head pinned to XCD via lin&7. Single-buffered staging.
// ---------------------------------------------------------------------------
__global__ __launch_bounds__(256, 2) void mha_attn(
    const short* __restrict__ qp, const short* __restrict__ kp,
    const short* __restrict__ vT, short* __restrict__ ctx)
{
    __shared__ short Ks[64][64];     // [key][dk]   (chunk-swizzled)
    __shared__ short Vs[64][64];     // [dv][key]   (chunk-swizzled)
    __shared__ short P[4][16][72];   // per-wave P[q][key], padded rows

    const int tid  = threadIdx.x;
    const int wid  = tid >> 6;
    const int lane = tid & 63;
    const int r16  = lane & 15;
    const int g    = lane >> 4;

    const int lin = blockIdx.x;           // 0..1023
    const int xcd = lin & 7;
    const int s8  = lin >> 3;             // 0..127
    const int bh  = (xcd << 2) | (s8 & 3);
    const int v   = s8 >> 2;              // 0..31
    const int grp = (v < 16) ? v : (47 - v);
    const int b   = bh >> 4;
    const int h   = bh & 15;

    const short* Qh = qp + (size_t)bh * SS * DKK;
    const short* Kh = kp + (size_t)bh * SS * DKK;
    const short* Vh = vT + (size_t)bh * SS * DKK;   // [DK][S]

    const int srow = lane >> 3;                     // 0..7
    const int csw  = (((lane & 7) ^ srow) & 7) * 8; // source-swizzled chunk
    const int r0   = wid * 16;                      // wave's staging stripe

    const int qr0 = grp * 64 + wid * 16;
    const int nkt = grp + 1;

    const s16x8 qf0 = *(const s16x8*)&Qh[(size_t)(qr0 + r16) * DKK + g * 8];
    const s16x8 qf1 = *(const s16x8*)&Qh[(size_t)(qr0 + r16) * DKK + 32 + g * 8];

    f32x4 po[4];
#pragma unroll
    for (int i = 0; i < 4; ++i) po[i] = (f32x4){0.f, 0.f, 0.f, 0.f};
    float lsum = 0.f;   // partial softmax denom for q = r16

#pragma unroll 1
    for (int j = 0; j < nkt; ++j) {
        const int k0 = j * 64;
        __syncthreads();   // protect Ks/Vs reuse
        {
            const int rowA = r0 + srow;
            const int rowB = rowA + 8;
            gload_lds16(&Kh[(size_t)(k0 + rowA) * DKK + csw], &Ks[r0][0]);
            gload_lds16(&Kh[(size_t)(k0 + rowB) * DKK + csw], &Ks[r0 + 8][0]);
            gload_lds16(&Vh[(size_t)rowA * SS + k0 + csw], &Vs[r0][0]);
            gload_lds16(&Vh[(size_t)rowB * SS + k0 + csw], &Vs[r0 + 8][0]);
        }
        __syncthreads();   // drain vmcnt: tiles ready

        // ---- swapped QK^T: T[key][q] = mfma(A=K, B=Q) ----
        f32x4 sc[4];
        __builtin_amdgcn_s_setprio(1);
#pragma unroll
        for (int cg = 0; cg < 4; ++cg) {
            const int R  = cg * 16 + r16;
            const int sw = R & 7;
            const s16x8 kf0 = *(const s16x8*)&Ks[R][((g ^ sw) & 7) * 8];
            const s16x8 kf1 = *(const s16x8*)&Ks[R][(((4 + g) ^ sw) & 7) * 8];
            f32x4 tt = (f32x4){0.f, 0.f, 0.f, 0.f};
            tt = __builtin_amdgcn_mfma_f32_16x16x32_bf16(kf0, qf0, tt, 0, 0, 0);
            tt = __builtin_amdgcn_mfma_f32_16x16x32_bf16(kf1, qf1, tt, 0, 0, 0);
            sc[cg] = tt;   // lane: q = r16, keys = k0 + cg*16 + g*4 + r
        }
        __builtin_amdgcn_s_setprio(0);

        // ---- causal mask (diag tile): key > q-row ----
        if (j == nkt - 1) {
#pragma unroll
            for (int cg = 0; cg < 4; ++cg)
#pragma unroll
                for (int r = 0; r < 4; ++r)
                    if (k0 + cg * 16 + g * 4 + r > qr0 + r16) sc[cg][r] = -1e9f;
        }
        // ---- softmax-lite: exp, lane-local sum, packed P write ----
#pragma unroll
        for (int cg = 0; cg < 4; ++cg) {
            const float p0 = __expf(sc[cg][0]);
            const float p1 = __expf(sc[cg][1]);
            const float p2 = __expf(sc[cg][2]);
            const float p3 = __expf(sc[cg][3]);
            lsum += (p0 + p1) + (p2 + p3);
            u32x2 w;
            w[0] = cvtpk(p0, p1);
            w[1] = cvtpk(p2, p3);
            *(u32x2*)&P[wid][r16][cg * 16 + g * 4] = w;   // ds_write_b64
        }
        // same-wave write->read: compiler inserts lgkmcnt wait
        const s16x8 pf0 = *(const s16x8*)&P[wid][r16][g * 8];
        const s16x8 pf1 = *(const s16x8*)&P[wid][r16][32 + g * 8];

        // ---- PV: A = P, B = V ----
        __builtin_amdgcn_s_setprio(1);
#pragma unroll
        for (int dg = 0; dg < 4; ++dg) {
            const int Rv = dg * 16 + r16;
            const int sw = Rv & 7;
            const s16x8 vf0 = *(const s16x8*)&Vs[Rv][((g ^ sw) & 7) * 8];
            const s16x8 vf1 = *(const s16x8*)&Vs[Rv][(((4 + g) ^ sw) & 7) * 8];
            po[dg] = __builtin_amdgcn_mfma_f32_16x16x32_bf16(pf0, vf0, po[dg], 0, 0, 0);
            po[dg] = __builtin_amdgcn_mfma_f32_16x16x32_bf16(pf1, vf1, po[dg], 0, 0, 0);
        }
        __builtin_amdgcn_s_setprio(0);
    }

    // ---- epilogue: finish denom, fetch per-row inverse, store ----
    lsum += __shfl_xor(lsum, 16);
    lsum += __shfl_xor(lsum, 32);   // lane now holds total for q = r16
    const float linv = __builtin_amdgcn_rcpf(lsum);
    float rowinv[4];
#pragma unroll
    for (int r = 0; r < 4; ++r)
        rowinv[r] = __shfl(linv, g * 4 + r);   // lane (g*4+r) has q = g*4+r
#pragma unroll
    for (int dg = 0; dg < 4; ++dg)
#pragma unroll
        for (int r = 0; r < 4; ++r) {
            const int srw = qr0 + g * 4 + r;
            const float vv = po[dg][r] * rowinv[r];
            ctx[((size_t)(b * SS + srw)) * DD + h * 64 + dg * 16 + r16] = f2bs(vv);
        }
}

// ---------------------------------------------------------------------------
extern "C" void kernel_launch(void* const* d_in, const int* in_sizes, int n_in,
                              void* d_out, int out_size, void* d_ws, size_t ws_size,
                              hipStream_t stream) {
    const float* query = (const float*)d_in[0];
    const float* key   = (const float*)d_in[1];
    const float* value = (const float*)d_in[2];
    // d_in[3] = mask (causal tril) -- implemented analytically
    const float* Wq = (const float*)d_in[4];
    const float* bq = (const float*)d_in[5];
    const float* Wk = (const float*)d_in[6];
    const float* bk = (const float*)d_in[7];
    const float* Wv = (const float*)d_in[8];
    const float* bv = (const float*)d_in[9];
    const float* Wo = (const float*)d_in[10];
    const float* bo = (const float*)d_in[11];
    float* out = (float*)d_out;

    const size_t elems = (size_t)BB * SS * DD;   // 4M
    const size_t wel   = (size_t)DD * DD;        // 1M
    short* wqx = (short*)d_ws;        // bf16 weights (8 MB)
    short* wkx = wqx + wel;
    short* wvx = wkx + wel;
    short* wox = wvx + wel;
    short* qp  = wox + wel;           // projections (24 MB)
    short* kp  = qp + elems;
    short* vp  = kp + elems;
    short* vT  = vp + elems;          // transposed V (8 MB)
    short* ctx = vT + elems;          // attention output (8 MB) -- 48 MB total

    // 1) convert weights to bf16 (24 MB traffic)
    cvt_w<<<dim3(512, 4), 256, 0, stream>>>(Wq, Wk, Wv, Wo, wqx, wkx, wvx, wox);
    // 2) fused Q/K/V projections (BM=128, BN=128, 768 blocks); A = fp32
    //    inputs converted during staging; 1/sqrt(DK) folded into Q
    gemm_nt_v2<128, 128, 3, false, true><<<dim3(768), 256, 0, stream>>>(
        query, key, value, wqx, wkx, wvx, bq, bk, bv, qp, kp, vp,
        0.125f, 1.0f, 1.0f, /*ppx=*/12, /*NY=*/32, /*KL=*/1024, DD, DD);
    // 3) V transpose per head (LDS-tiled, coalesced both ways)
    mha_transpose_v<<<dim3(SS / 64, BB * HH), 256, 0, stream>>>(vp, vT);
    // 4) attention -> ctx: r15 structure (proven 40.7us)
    mha_attn<<<dim3(1024), 256, 0, stream>>>(qp, kp, vT, ctx);
    // 5) output projection: BM=64, BN=64 -> 1024 blocks = 4/CU
    gemm_nt_v2<64, 64, 4, true, false><<<dim3(1024), 256, 0, stream>>>(
        ctx, ctx, ctx, wox, wox, wox, bo, bo, bo, out, out, out,
        1.0f, 1.0f, 1.0f, /*ppx=*/8, /*NY=*/64, /*KL=*/1024, DD, DD);
}